// Round 5
// baseline (287.532 us; speedup 1.0000x reference)
//
#include <hip/hip_runtime.h>
#include <math.h>

// QuantizedAttention: B=2, S=2048, D=1024, H=16, Dh=64.
// Round 10 (= round 9 resubmit; container infra failure, kernel re-audited):
//  - flash_mfma8: attack the invariant ~18K-cycle iteration (r5-r8 all ~2.1
//    wave-iters/us/CU regardless of occupancy/balance -> lockstep phase sum).
//    (1) double-buffered Ks/Vs -> ONE barrier/iter; staging writes overlap
//        compute instead of sitting between two barriers.
//    (2) P stays in registers: permlane32_swap exchanges the h2 (lane+-32)
//        halves -> PV B-frags built in-reg; P2 LDS round-trip removed
//        (8 ds_write_b64 + 4 ds_read_b128 per wave-iter gone).
//    (3) tree max/sum (depth 31->5), exp2-direct with folded scale.
//    (4) s_setprio(1) around MFMA clusters.
//    LDS 131072B: Ks[2][4][4096] | Vs[2][4][4096]; merge mbuf/Osb overlay
//    post-loop. Grid/pairing/kv-split-4/4-way LSE merge identical to r8.
//  - hardening vs r9: explicit 16B alignment on sbuf (uint4 LDS accesses).
//  - everything else identical to round 8 (verified).

typedef __attribute__((ext_vector_type(8))) short bf16x8;   // 8 bf16 = 4 VGPRs
typedef __attribute__((ext_vector_type(16))) float f32x16;
typedef __attribute__((ext_vector_type(4))) float f32x4;
typedef __attribute__((ext_vector_type(4))) float f4;

#define E4M3_MAX 448.0f

#if __has_builtin(__builtin_amdgcn_exp2f)
#define FEXP2(x) __builtin_amdgcn_exp2f(x)
#else
#define FEXP2(x) exp2f(x)
#endif

__device__ inline float bf2f(ushort u) { return __uint_as_float(((unsigned)u) << 16); }
__device__ inline ushort f2bf(float f) {
  unsigned u = __float_as_uint(f);
  return (ushort)((u + 0x7FFF + ((u >> 16) & 1)) >> 16);  // RNE
}
__device__ inline unsigned pack2bf(float a, float b) {  // round-half-up
  unsigned ua = __float_as_uint(a), ub = __float_as_uint(b);
  return ((ua + 0x8000u) >> 16) | ((ub + 0x8000u) & 0xFFFF0000u);
}

// swap lanes[32:63] of a with lanes[0:31] of b (v_permlane32_swap_b32):
// a_new = {a_lo, b_lo}, b_new = {a_hi, b_hi}.
__device__ __forceinline__ void pl32swap(unsigned& a, unsigned& b, int h2) {
#if __has_builtin(__builtin_amdgcn_permlane32_swap)
  typedef __attribute__((ext_vector_type(2))) int i32x2;
  i32x2 r = __builtin_amdgcn_permlane32_swap((int)a, (int)b, false, false);
  a = (unsigned)r[0];
  b = (unsigned)r[1];
#else
  unsigned pa = (unsigned)__shfl_xor((int)a, 32);
  unsigned pb = (unsigned)__shfl_xor((int)b, 32);
  unsigned na = h2 ? pb : a;
  unsigned nb = h2 ? b : pa;
  a = na;
  b = nb;
#endif
}

// async 16B global -> LDS (direct-to-shared DMA). LDS dest must be
// wave-uniform base + lane*16 — all call sites below satisfy that.
__device__ __forceinline__ void gll16(const ushort* g, ushort* l) {
  __builtin_amdgcn_global_load_lds(
      (const __attribute__((address_space(1))) unsigned int*)g,
      (__attribute__((address_space(3))) unsigned int*)l, 16, 0, 0);
}

__global__ void zero16_kernel(float* p) {
  if (threadIdx.x < 16) p[threadIdx.x] = 0.0f;
}

// 6 tensors in one launch; y selects. Nonneg-float uint atomicMax.
__global__ __launch_bounds__(256) void amax6_kernel(const float* __restrict__ p0,
                                                    const float* __restrict__ p1,
                                                    const float* __restrict__ p2,
                                                    const float* __restrict__ p3,
                                                    const float* __restrict__ p4,
                                                    const float* __restrict__ p5,
                                                    float* __restrict__ amax) {
  int y = blockIdx.y;
  const float* src = (y == 0) ? p0 : (y == 1) ? p1 : (y == 2) ? p2 : (y == 3) ? p3 : (y == 4) ? p4 : p5;
  int n = (y < 3) ? 1048576 : 1024;
  float m = 0.0f;
  int stride = gridDim.x * 256;
  for (int i = blockIdx.x * 256 + threadIdx.x; i < n; i += stride)
    m = fmaxf(m, fabsf(src[i]));
  #pragma unroll
  for (int off = 32; off > 0; off >>= 1)
    m = fmaxf(m, __shfl_xor(m, off));
  __shared__ float wred[4];
  if ((threadIdx.x & 63) == 0) wred[threadIdx.x >> 6] = m;
  __syncthreads();
  if (threadIdx.x == 0) {
    m = fmaxf(fmaxf(wred[0], wred[1]), fmaxf(wred[2], wred[3]));
    atomicMax((unsigned int*)(amax + y), __float_as_uint(m));
  }
}

// e4m3 GRID value (no descale) -- exactly representable in bf16.
__device__ inline float qdq_qval(float w, float amax) {
  float scale = E4M3_MAX / fmaxf(amax, 1e-12f);
  float v = w * scale;
  float a = fmaxf(fabsf(v), 1e-30f);
  int ex;
  (void)frexpf(a, &ex);                 // floor(log2(a)) = ex-1
  float e = fminf(fmaxf((float)(ex - 1), -6.0f), 8.0f);
  float step = exp2f(e - 3.0f);
  float q = rintf(v / step) * step;     // round-half-even matches jnp.round
  return fminf(fmaxf(q, -E4M3_MAX), E4M3_MAX);
}

// 3 bias vectors, one launch (y selects); writes dequantized fp32.
__global__ void qvec3_kernel(const float* __restrict__ b0, const float* __restrict__ b1,
                             const float* __restrict__ b2, const float* __restrict__ amax,
                             float* __restrict__ o0, float* __restrict__ o1,
                             float* __restrict__ o2) {
  int y = blockIdx.y;
  const float* b = (y == 0) ? b0 : (y == 1) ? b1 : b2;
  float* o = (y == 0) ? o0 : (y == 1) ? o1 : o2;
  float am = amax[3 + y];
  int idx = blockIdx.x * blockDim.x + threadIdx.x;
  if (idx < 1024) {
    float q = qdq_qval(b[idx], am);
    o[idx] = q * (fmaxf(am, 1e-12f) * (1.0f / E4M3_MAX));
  }
}

// W [H=16][D=1024][Dh=64] fp32 -> Bt [he=1024][d=1024] bf16 grid values; z selects.
__global__ __launch_bounds__(256) void quant_repack_bt3(const float* __restrict__ W0,
                                                        const float* __restrict__ W1,
                                                        const float* __restrict__ W2,
                                                        const float* __restrict__ amaxp,
                                                        ushort* __restrict__ o0,
                                                        ushort* __restrict__ o1,
                                                        ushort* __restrict__ o2) {
  int z = blockIdx.z;
  const float* W = (z == 0) ? W0 : (z == 1) ? W1 : W2;
  ushort* Bt = (z == 0) ? o0 : (z == 1) ? o1 : o2;
  float amax = amaxp[z];
  __shared__ float tile[64][65];
  int d0 = blockIdx.x * 64, hh = blockIdx.y;
  int tid = threadIdx.x;
  int e = tid & 63, dd = tid >> 6;
  #pragma unroll
  for (int p = 0; p < 16; p++)
    tile[dd + p * 4][e] = W[(size_t)hh * 65536 + (size_t)(d0 + dd + p * 4) * 64 + e];
  __syncthreads();
  int d = tid & 63, ee = tid >> 6;
  #pragma unroll
  for (int p = 0; p < 16; p++) {
    int e2 = ee + p * 4;
    Bt[(size_t)(hh * 64 + e2) * 1024 + d0 + d] = f2bf(qdq_qval(tile[d][e2], amax));
  }
}

// W_O [he=1024][d=1024] fp32 -> woT [d][he] bf16
__global__ __launch_bounds__(256) void wo_trans(const float* __restrict__ W,
                                               ushort* __restrict__ Bt) {
  __shared__ float tile[64][65];
  int d0 = blockIdx.x * 64, he0 = blockIdx.y * 64;
  int tid = threadIdx.x;
  int dcol = tid & 63, hr = tid >> 6;
  #pragma unroll
  for (int p = 0; p < 16; p++)
    tile[hr + p * 4][dcol] = W[(size_t)(he0 + hr + p * 4) * 1024 + d0 + dcol];
  __syncthreads();
  int hcol = tid & 63, dr = tid >> 6;
  #pragma unroll
  for (int p = 0; p < 16; p++)
    Bt[(size_t)(d0 + dr + p * 4) * 1024 + he0 + hcol] = f2bf(tile[hcol][dr + p * 4]);
}

// fp32 -> bf16, 3 tensors in one launch (y selects), 4 elems/thread. grid.x = 4096.
__global__ __launch_bounds__(256) void cvt3_kernel(const float* __restrict__ i0,
                                                   const float* __restrict__ i1,
                                                   const float* __restrict__ i2,
                                                   ushort* __restrict__ o0,
                                                   ushort* __restrict__ o1,
                                                   ushort* __restrict__ o2) {
  int y = blockIdx.y;
  const float* in = (y == 0) ? i0 : (y == 1) ? i1 : i2;
  ushort* out = (y == 0) ? o0 : (y == 1) ? o1 : o2;
  int i = blockIdx.x * 256 + threadIdx.x;
  f4 v = *(const f4*)(in + (size_t)i * 4);
  uint2 o;
  o.x = (unsigned)f2bf(v[0]) | ((unsigned)f2bf(v[1]) << 16);
  o.y = (unsigned)f2bf(v[2]) | ((unsigned)f2bf(v[3]) << 16);
  *(uint2*)(out + (size_t)i * 4) = o;
}

// GEMM body: C = A[M=4096][K=1024] x Bt[N][K]^T, tile 128 x TN, BK=32, 256 thr.
// m97-style: global_load_lds(16B) into UNPADDED LDS; wave-uniform dest = base+lane*16.
// QUANT=1: out bf16 *s_inv+bias; QUANT=0: out fp32 +bias.
template <int QUANT, int TN>
__device__ __forceinline__ void gemm_body(const ushort* __restrict__ A,
                                          const ushort* __restrict__ Bt,
                                          const float* __restrict__ bias, float s_inv,
                                          ushort* __restrict__ outb, float* __restrict__ outf,
                                          int bx, int by, ushort* As, ushort* Bs) {
  const int K = 1024, N = 1024;
  const int JF = TN / 32;                 // j-frags per wave
  int tid = threadIdx.x;
  int w = tid >> 6, lane = tid & 63, quad = lane >> 4, l16 = lane & 15;
  int wm = w & 1, wn = w >> 1;
  int row0 = by * 128, col0 = bx * TN;
  f32x4 acc[4][4] = {};

  for (int k0 = 0; k0 < K; k0 += 32) {
    __syncthreads();
    {
      int u = tid;                        // A tile: 128x32 = 512 units of 16B
      gll16(&A[(size_t)(row0 + (u >> 2)) * K + k0 + (u & 3) * 8], &As[u * 8]);
      u = tid + 256;
      gll16(&A[(size_t)(row0 + (u >> 2)) * K + k0 + (u & 3) * 8], &As[u * 8]);
      u = tid;                            // B tile: TN x 32 = TN*4 units
      gll16(&Bt[(size_t)(col0 + (u >> 2)) * K + k0 + (u & 3) * 8], &Bs[u * 8]);
      if (TN == 128) {
        u = tid + 256;
        gll16(&Bt[(size_t)(col0 + (u >> 2)) * K + k0 + (u & 3) * 8], &Bs[u * 8]);
      }
    }
    __syncthreads();                      // compiler drains vmcnt before barrier
    bf16x8 af[4], bfr[JF];
    #pragma unroll
    for (int i = 0; i < 4; i++)
      af[i] = *(const bf16x8*)&As[(wm * 64 + i * 16 + l16) * 32 + quad * 8];
    #pragma unroll
    for (int j = 0; j < JF; j++)
      bfr[j] = *(const bf16x8*)&Bs[(wn * (TN / 2) + j * 16 + l16) * 32 + quad * 8];
    #pragma unroll
    for (int i = 0; i < 4; i++)
      #pragma unroll
      for (int j = 0; j < JF; j++)
        acc[i][j] = __builtin_amdgcn_mfma_f32_16x16x32_bf16(af[i], bfr[j], acc[i][j], 0, 0, 0);
  }

  #pragma unroll
  for (int j = 0; j < JF; j++) {
    int col = col0 + wn * (TN / 2) + j * 16 + l16;
    float bv = bias[col];
    #pragma unroll
    for (int i = 0; i < 4; i++) {
      int row = row0 + wm * 64 + i * 16 + quad * 4;
      #pragma unroll
      for (int r = 0; r < 4; r++) {
        float v = acc[i][j][r] * s_inv + bv;
        if (QUANT) outb[(size_t)(row + r) * N + col] = f2bf(v);
        else       outf[(size_t)(row + r) * N + col] = v;
      }
    }
  }
}

// Batched QKV projection: grid (8, 32, 3) = 768 blocks.
__global__ __launch_bounds__(256) void gemm3_qkv(const ushort* __restrict__ xq,
                                                 const ushort* __restrict__ xk,
                                                 const ushort* __restrict__ xv,
                                                 const ushort* __restrict__ wq,
                                                 const ushort* __restrict__ wk,
                                                 const ushort* __restrict__ wv,
                                                 const float* __restrict__ bq,
                                                 const float* __restrict__ bk,
                                                 const float* __restrict__ bv,
                                                 const float* __restrict__ amax,
                                                 ushort* __restrict__ oq,
                                                 ushort* __restrict__ ok,
                                                 ushort* __restrict__ ov) {
  __shared__ ushort As[4096], Bs[4096];
  int z = blockIdx.z;
  const ushort* A  = (z == 0) ? xq : (z == 1) ? xk : xv;
  const ushort* Bt = (z == 0) ? wq : (z == 1) ? wk : wv;
  const float* bias = (z == 0) ? bq : (z == 1) ? bk : bv;
  ushort* out = (z == 0) ? oq : (z == 1) ? ok : ov;
  float s_inv = fmaxf(amax[z], 1e-12f) * (1.0f / E4M3_MAX);
  gemm_body<1, 128>(A, Bt, bias, s_inv, out, nullptr, blockIdx.x, blockIdx.y, As, Bs);
}

// Output projection: 128x64 tile -> grid (16, 32) = 512 blocks (2/CU).
__global__ __launch_bounds__(256) void gemm_wo(const ushort* __restrict__ A,
                                               const ushort* __restrict__ Bt,
                                               const float* __restrict__ bias,
                                               float* __restrict__ out) {
  __shared__ ushort As[4096], Bs[2048];
  gemm_body<0, 64>(A, Bt, bias, 1.0f, nullptr, out, blockIdx.x, blockIdx.y, As, Bs);
}

// In-place rotary on bf16 q/k (unchanged).
__global__ __launch_bounds__(256) void rotary_bf(ushort* qb, ushort* kb) {
  int bs = blockIdx.x;
  int s = bs & 2047;
  int tid = threadIdx.x;
  int e = tid & 63, w = tid >> 6;
  int j = e & 31;
  float inv_freq = exp2f((float)j * (-13.287712379549449f / 32.0f));
  float ang = (float)s * inv_freq;
  float c = cosf(ang), sn = sinf(ang);
  float sgn = (e < 32) ? -1.0f : 1.0f;
  size_t base = (size_t)bs * 1024;
  #pragma unroll
  for (int i = 0; i < 4; i++) {
    int h = w + i * 4;
    size_t idx = base + (size_t)h * 64 + e;
    float x = bf2f(qb[idx]);
    float xp = __shfl_xor(x, 32);
    qb[idx] = f2bf(x * c + sgn * xp * sn);
    float y = bf2f(kb[idx]);
    float yp = __shfl_xor(y, 32);
    kb[idx] = f2bf(y * c + sgn * yp * sn);
  }
}

// v [bs][he] bf16 -> vT [(b*16+h)*64+e][s] bf16 (unchanged).
__global__ __launch_bounds__(256) void v_trans(const ushort* __restrict__ v,
                                              ushort* __restrict__ vT) {
  __shared__ ushort tile[64][72];
  int s0 = blockIdx.x * 64, h = blockIdx.y, b = blockIdx.z;
  int tid = threadIdx.x;
  int e = tid & 63, sr = tid >> 6;
  #pragma unroll
  for (int p = 0; p < 16; p++)
    tile[sr + p * 4][e] = v[(size_t)(b * 2048 + s0 + sr + p * 4) * 1024 + h * 64 + e];
  __syncthreads();
  int sc = tid & 63, er = tid >> 6;
  #pragma unroll
  for (int p = 0; p < 16; p++)
    vT[(size_t)((b * 16 + h) * 64 + er + p * 4) * 2048 + s0 + sc] = tile[sc][er + p * 4];
}

// ---- Flash v8: dbuf K/V (1 barrier/iter) + in-register P (permlane32_swap)
//      + tree reductions + exp2-direct + setprio. ----
// Grid (8, 16, 2), 1024 thr / 16 waves (4 q-waves x kv-split-4), 1 block/CU.
// Block bx processes q-tiles (15-bx) then (bx) (uniform per-CU work).
// LDS (ushorts): Ks[buf][g] = sbuf + buf*16384 + g*4096;
//                Vs[buf][g] = sbuf + 32768 + buf*16384 + g*4096.  (131072 B)
// Merge (post-loop overlay): mbuf = (float*)sbuf, 768x35 f32 (107520 B);
//                            Osb  = sbuf + 53760 (128x72 bf16, 18432 B).
__global__ __launch_bounds__(1024, 4) void flash_mfma8(const ushort* __restrict__ qb,
                                                       const ushort* __restrict__ kb,
                                                       const ushort* __restrict__ vT,
                                                       ushort* __restrict__ zb) {
  int h = blockIdx.y, b = blockIdx.z;
  int tid = threadIdx.x;
  int g = tid >> 8;                      // kv split 0..3
  int w = (tid >> 6) & 3;                // q-wave 0..3
  int lane = tid & 63, h2 = lane >> 5, l31 = lane & 31;
  __shared__ __align__(16) ushort sbuf[65536];   // 131072 B

  const int qrow = w * 32 + l31;         // block-local q row
  const float CE = 0.125f;               // 1/sqrt(64)
  const float SCL = 0.180336880f;        // CE * log2(e)

  // staging geometry (per split: its 256 threads stage 64x64 K and V tiles)
  const int ts = tid & 255;
  const int u0 = ts, u1 = ts + 256;
  const int r0 = u0 >> 3, c0 = u0 & 7, r1 = u1 >> 3, c1 = u1 & 7;
  const int sw0 = (c0 ^ (r0 & 7)) * 8, sw1 = (c1 ^ (r1 & 7)) * 8;
  const int kgo = g * 4096;              // split offset within a buffer

  #pragma unroll 1
  for (int rep = 0; rep < 2; rep++) {
    const int qt = (rep == 0) ? (15 - (int)blockIdx.x) : (int)blockIdx.x;
    const int q0 = qt * 128;
    const int qg = q0 + w * 32 + l31;    // this lane's q (column of S^T)
    size_t qbase = ((size_t)(b * 2048 + qg)) * 1024 + (size_t)h * 64;
    bf16x8 qf[4];                        // Q B-frags: slot (h2,j) of chunk ck <- e=16ck+8h2+j
    #pragma unroll
    for (int ck = 0; ck < 4; ck++)
      qf[ck] = *(const bf16x8*)&qb[qbase + ck * 16 + h2 * 8];

    f32x16 accO[2] = {};                 // O^T: rows e (2 frags), col q
    float mrun = -INFINITY, lrun = 0.0f;

    // kv-split-4 ranges: T = 2qt+2 tiles total, split into ceil/floor shares
    const int T = 2 * qt + 2;
    const int qd = T >> 2, rr = T & 3;   // rr in {0,2}
    const int nt = qd + (g < rr ? 1 : 0);
    const int kt0 = g * qd + (g < rr ? g : rr);
    const int ntmax = qd + (rr ? 1 : 0);

    const ushort* ksrc0 = kb + ((size_t)(b * 2048 + kt0 * 64 + r0)) * 1024 + (size_t)h * 64 + c0 * 8;
    const ushort* ksrc1 = kb + ((size_t)(b * 2048 + kt0 * 64 + r1)) * 1024 + (size_t)h * 64 + c1 * 8;
    const ushort* vsrc0 = vT + ((size_t)((b * 16 + h) * 64 + r0)) * 2048 + kt0 * 64 + c0 * 8;
    const ushort* vsrc1 = vT + ((size_t)((b * 16 + h) * 64 + r1)) * 2048 + kt0 * 64 + c1 * 8;

    uint4 kc0, kc1, vc0, vc1;
    if (nt > 0) {                        // tile 0 -> buf0 (direct)
      kc0 = *(const uint4*)ksrc0;
      kc1 = *(const uint4*)ksrc1;
      vc0 = *(const uint4*)vsrc0;
      vc1 = *(const uint4*)vsrc1;
      *(uint4*)&sbuf[kgo + r0 * 64 + sw0] = kc0;
      *(uint4*)&sbuf[kgo + r1 * 64 + sw1] = kc1;
      *(uint4*)&sbuf[32768 + kgo + r0 * 64 + sw0] = vc0;
      *(uint4*)&sbuf[32768 + kgo + r1 * 64 + sw1] = vc1;
      if (nt > 1) {                      // tile 1 -> regs
        kc0 = *(const uint4*)(ksrc0 + 65536);
        kc1 = *(const uint4*)(ksrc1 + 65536);
        vc0 = *(const uint4*)(vsrc0 + 64);
        vc1 = *(const uint4*)(vsrc1 + 64);
      }
    }
    __syncthreads();

    for (int t = 0; t < ntmax; t++) {
      const int bufc = (t & 1) << 14;    // current buffer (ushort offset)
      const int bufn = bufc ^ 16384;     // next buffer
      if (t + 1 < nt) {                  // regs (tile t+1) -> next buffer
        *(uint4*)&sbuf[bufn + kgo + r0 * 64 + sw0] = kc0;
        *(uint4*)&sbuf[bufn + kgo + r1 * 64 + sw1] = kc1;
        *(uint4*)&sbuf[32768 + bufn + kgo + r0 * 64 + sw0] = vc0;
        *(uint4*)&sbuf[32768 + bufn + kgo + r1 * 64 + sw1] = vc1;
      }
      if (t + 2 < nt) {                  // prefetch tile t+2 -> regs
        kc0 = *(const uint4*)(ksrc0 + (size_t)(t + 2) * 65536);
        kc1 = *(const uint4*)(ksrc1 + (size_t)(t + 2) * 65536);
        vc0 = *(const uint4*)(vsrc0 + (t + 2) * 64);
        vc1 = *(const uint4*)(vsrc1 + (t + 2) * 64);
      }

      int kt = kt0 + t;                  // global kv tile index
      bool active = (t < nt) && (kt * 64 <= q0 + w * 32 + 31);
      if (active) {
        const ushort* Kc = sbuf + bufc + kgo;
        const ushort* Vc = sbuf + 32768 + bufc + kgo;

        // S^T = K . Q^T   (M=kv 2 frags of 32, K=e in 4 chunks of 16)
        f32x16 sc[2] = {};
        __builtin_amdgcn_s_setprio(1);
        #pragma unroll
        for (int mf = 0; mf < 2; mf++) {
          int row = mf * 32 + l31;
          int s8 = row & 7;
          #pragma unroll
          for (int ck = 0; ck < 4; ck++) {
            bf16x8 ka = *(const bf16x8*)&Kc[row * 64 + (((2 * ck + h2) ^ s8) * 8)];
            sc[mf] = __builtin_amdgcn_mfma_f32_32x32x16_bf16(ka, qf[ck], sc[mf], 0, 0, 0);
          }
        }
        __builtin_amdgcn_s_setprio(0);

        // causal mask (raw domain: -8000 * 0.125 = -1000 matches ref IGNORE)
        if (kt * 64 + 63 > q0 + w * 32) {
          #pragma unroll
          for (int mf = 0; mf < 2; mf++)
            #pragma unroll
            for (int i = 0; i < 16; i++) {
              int kv = kt * 64 + mf * 32 + (i & 3) + 8 * (i >> 2) + 4 * h2;
              sc[mf][i] = (kv > qg) ? -8000.0f : sc[mf][i];
            }
        }

        // online softmax: in-register, tree max (depth 5) + one xor-32 shuffle
        float mx[16];
        #pragma unroll
        for (int i = 0; i < 16; i++) mx[i] = fmaxf(sc[0][i], sc[1][i]);
        #pragma unroll
        for (int s2 = 8; s2; s2 >>= 1)
          #pragma unroll
          for (int i = 0; i < s2; i++) mx[i] = fmaxf(mx[i], mx[i + s2]);
        float tm = fmaxf(mx[0], __shfl_xor(mx[0], 32));
        float mnew = fmaxf(mrun, tm);
        float alpha = FEXP2((mrun - mnew) * SCL);
        float msc = mnew * SCL;

        // p = exp2(sc*SCL - msc); pack pairs for PV; tree sum
        unsigned pu[2][4], pv[2][4];
        float sm[16];
        #pragma unroll
        for (int mf = 0; mf < 2; mf++)
          #pragma unroll
          for (int m = 0; m < 4; m++) {
            float p0 = FEXP2(fmaf(sc[mf][4 * m + 0], SCL, -msc));
            float p1 = FEXP2(fmaf(sc[mf][4 * m + 1], SCL, -msc));
            float p2 = FEXP2(fmaf(sc[mf][4 * m + 2], SCL, -msc));
            float p3 = FEXP2(fmaf(sc[mf][4 * m + 3], SCL, -msc));
            pu[mf][m] = pack2bf(p0, p1);
            pv[mf][m] = pack2bf(p2, p3);
            sm[mf * 8 + m] = p0 + p1;
            sm[mf * 8 + 4 + m] = p2 + p3;
          }
        #pragma unroll
        for (int s2 = 8; s2; s2 >>= 1)
          #pragma unroll
          for (int i = 0; i < s2; i++) sm[i] += sm[i + s2];
        float rs = sm[0] + __shfl_xor(sm[0], 32);
        lrun = lrun * alpha + rs;
        mrun = mnew;
        #pragma unroll
        for (int mf = 0; mf < 2; mf++)
          #pragma unroll
          for (int i = 0; i < 16; i++) accO[mf][i] *= alpha;

        // O^T += V^T . P^T ; P B-frags built in-register via permlane32_swap:
        // word0/2 = swap(pu[ms][2cl], pu[ms][2cl+1]); word1/3 = swap(pv...).
        __builtin_amdgcn_s_setprio(1);
        #pragma unroll
        for (int ck = 0; ck < 4; ck++) {
          int ms = ck >> 1, cl = ck & 1;
          unsigned w0 = pu[ms][2 * cl], w2 = pu[ms][2 * cl + 1];
          unsigned w1 = pv[ms][2 * cl], w3 = pv[ms][2 * cl + 1];
          pl32swap(w0, w2, h2);
          pl32swap(w1, w3, h2);
          union { unsigned u[4]; bf16x8 v8; } pb_;
          pb_.u[0] = w0; pb_.u[1] = w1; pb_.u[2] = w2; pb_.u[3] = w3;
          #pragma unroll
          for (int mf = 0; mf < 2; mf++) {
            int row = mf * 32 + l31;
            bf16x8 va = *(const bf16x8*)&Vc[row * 64 + (((2 * ck + h2) ^ (row & 7)) * 8)];
            accO[mf] = __builtin_amdgcn_mfma_f32_32x32x16_bf16(va, pb_.v8, accO[mf], 0, 0, 0);
          }
        }
        __builtin_amdgcn_s_setprio(0);
      }
      __syncthreads();                   // buf swap: all reads of bufc done
    }

    // ---- merge the four kv-splits: log-sum-exp combine through LDS ----
    // (last loop barrier already ordered all LDS reads before this overlay)
    float* mbuf = (float*)sbuf;          // (g-1,w,lane) x 35 floats
    if (g > 0) {
      int midx = ((g - 1) * 256 + w * 64 + lane) * 35;
      #pragma unroll
      for (int i = 0; i < 16; i++) mbuf[midx + i] = accO[0][i];
      #pragma unroll
      for (int i = 0; i < 16; i++) mbuf[midx + 16 + i] = accO[1][i];
      mbuf[midx + 32] = mrun;
      mbuf[midx + 33] = lrun;
    }
    __syncthreads();
    ushort* Osb = sbuf + 53760;          // 128 x 72 (past mbuf region)
    if (g == 0) {
      int i1 = (w * 64 + lane) * 35;
      int i2 = (256 + w * 64 + lane) * 35;
      int i3 = (512 + w * 64 + lane) * 35;
      float m1 = mbuf[i1 + 32], l1 = mbuf[i1 + 33];
      float m2 = mbuf[i2 + 32], l2 = mbuf[i2 + 33];
      float m3 = mbuf[i3 + 32], l3 = mbuf[i3 + 33];
      float mn = fmaxf(fmaxf(mrun, m1), fmaxf(m2, m3));
      float a0 = __expf((mrun - mn) * CE), a1 = __expf((m1 - mn) * CE);
      float a2 = __expf((m2 - mn) * CE), a3 = __expf((m3 - mn) * CE);
      float linv = 1.0f / (lrun * a0 + l1 * a1 + l2 * a2 + l3 * a3);
      #pragma unroll
      for (int mf = 0; mf < 2; mf++)
        #pragma unroll
        for (int m = 0; m < 4; m++) {
          int idx = 16 * mf + 4 * m;
          int e0 = 32 * mf + 8 * m + 4 * h2;
          float o0 = (accO[mf][4 * m + 0] * a0 + mbuf[i1 + idx + 0] * a1 + mbuf[i2 + idx + 0] * a2 + mbuf[i3 + idx + 0] * a3) * linv;
          float o1 = (accO[mf][4 * m + 1] * a0 + mbuf[i1 + idx + 1] * a1 + mbuf[i2 + idx + 1] * a2 + mbuf[i3 + idx + 1] * a3) * linv;
          float o2 = (accO[mf][4 * m + 2] * a0 + mbuf[i1 + idx + 2] * a1 + mbuf[i2 + idx + 2] * a2 + mbuf[i3 + idx + 2] * a3) * linv;
          float o3 = (accO[mf][4 * m + 3] * a0 + mbuf[i1 + idx + 3] * a1 + mbuf[i2 + idx + 3] * a2 + mbuf[i3 + idx + 3] * a3) * linv;
          *(unsigned*)&Osb[qrow * 72 + e0] = pack2bf(o0, o1);
          *(unsigned*)&Osb[qrow * 72 + e0 + 2] = pack2bf(o2, o3);
        }
    }
    __syncthreads();
    size_t obase = ((size_t)(b * 2048 + q0)) * 1024 + (size_t)h * 64;
    {
      int u = tid;                       // 1024 units: 128 rows x 8 blocks
      int r = u >> 3, blk = u & 7;
      *(uint4*)&zb[obase + (size_t)r * 1024 + blk * 8] = *(const uint4*)&Osb[r * 72 + blk * 8];
    }
    __syncthreads();                     // Osb reads done before next rep's staging
  }
}

extern "C" void kernel_launch(void* const* d_in, const int* in_sizes, int n_in,
                              void* d_out, int out_size, void* d_ws, size_t ws_size,
                              hipStream_t stream) {
  const float* Xq  = (const float*)d_in[0];
  const float* Xk  = (const float*)d_in[1];
  const float* Xv  = (const float*)d_in[2];
  const float* W_Q = (const float*)d_in[3];
  const float* W_K = (const float*)d_in[4];
  const float* W_V = (const float*)d_in[5];
  const float* W_O = (const float*)d_in[6];
  const float* b_Q = (const float*)d_in[7];
  const float* b_K = (const float*)d_in[8];
  const float* b_V = (const float*)d_in[9];
  const float* b_O = (const float*)d_in[10];
  float* out = (float*)d_out;

  // ws layout (56.4 MB): amax/bias | weights 8.4MB | xq,xk,xv | qbf,kbf,vbf
  // vT overlays xq (dead after gemm3), zbf overlays xk (dead after gemm3/v_trans).
  char* base = (char*)d_ws;
  float*  amax = (float*)(base + 0);
  float*  bq   = (float*)(base + 4096);
  float*  bk   = (float*)(base + 8192);
  float*  bv   = (float*)(base + 12288);
  ushort* wq   = (ushort*)(base + 16384);
  ushort* wk   = (ushort*)(base + 16384 + 2097152);
  ushort* wv   = (ushort*)(base + 16384 + 2u * 2097152);
  ushort* woT  = (ushort*)(base + 16384 + 3u * 2097152);
  ushort* xq   = (ushort*)(base + 8404992);
  ushort* xk   = (ushort*)(base + 16793600);
  ushort* xv   = (ushort*)(base + 25182208);
  ushort* qbf  = (ushort*)(base + 33570816);
  ushort* kbf  = (ushort*)(base + 41959424);
  ushort* vbf  = (ushort*)(base + 50348032);
  ushort* vT   = xq;   // xq dead after gemm3_qkv
  ushort* zbf  = xk;   // xk dead after gemm3_qkv

  zero16_kernel<<<1, 64, 0, stream>>>(amax);
  dim3 agrid(64, 6);
  amax6_kernel<<<agrid, 256, 0, stream>>>(W_Q, W_K, W_V, b_Q, b_K, b_V, amax);

  dim3 rgrid(16, 16, 3);
  quant_repack_bt3<<<rgrid, 256, 0, stream>>>(W_Q, W_K, W_V, amax, wq, wk, wv);
  dim3 qvgrid(4, 3);
  qvec3_kernel<<<qvgrid, 256, 0, stream>>>(b_Q, b_K, b_V, amax, bq, bk, bv);
  dim3 wgrid(16, 16);
  wo_trans<<<wgrid, 256, 0, stream>>>(W_O, woT);
  dim3 cgrid(4096, 3);
  cvt3_kernel<<<cgrid, 256, 0, stream>>>(Xq, Xk, Xv, xq, xk, xv);

  dim3 g3(8, 32, 3);   // batched QKV: 768 blocks ~3/CU
  gemm3_qkv<<<g3, 256, 0, stream>>>(xq, xk, xv, wq, wk, wv, bq, bk, bv, amax,
                                    qbf, kbf, vbf);

  rotary_bf<<<4096, 256, 0, stream>>>(qbf, kbf);

  dim3 vgrid(32, 16, 2);
  v_trans<<<vgrid, 16 * 16, 0, stream>>>(vbf, vT);

  dim3 fgrid(8, 16, 2);   // q-tile pairs (15-bx, bx); 1024 thr = 16 waves
  flash_mfma8<<<fgrid, 1024, 0, stream>>>(qbf, kbf, vT, zbf);

  dim3 wog(16, 32);    // 128x64 tiles: 512 blocks (2/CU)
  gemm_wo<<<wog, 256, 0, stream>>>(zbf, woT, b_O, out);
}

// Round 6
// 253.467 us; speedup vs baseline: 1.1344x; 1.1344x over previous
//
#include <hip/hip_runtime.h>
#include <math.h>

// QuantizedAttention: B=2, S=2048, D=1024, H=16, Dh=64.
// Round 11:
//  - POST-MORTEM r9/r10: 1024-thr flash spilled (VGPR cap 128 at 16 waves/blk;
//    WRITE_SIZE 8.2->57MB across r0->r10 = scratch traffic). Reverted flash to
//    r2's flash_mfma6 VERBATIM (measured 60.3us, best).
//  - Launch-count attack: ~125us of the 270 total is inter-launch overhead
//    (11 serial launches, ~85us of real non-flash work). Fused to 6 launches:
//      prep1  = amax partials (no atomics, no zero16) + cvt3   [1D 12672 blks]
//      prep2  = quant_repack + qvec + wo_trans (self-reduce partials;
//               designated blocks write final amax[0..2])      [1D 1036 blks]
//      gemm3_qkv (unchanged)
//      rot_vtrans = rotary_bf + v_trans                        [1D 5120 blks]
//      flash_mfma6 (r2 verbatim)
//      gemm_wo (unchanged)

typedef __attribute__((ext_vector_type(8))) short bf16x8;   // 8 bf16 = 4 VGPRs
typedef __attribute__((ext_vector_type(16))) float f32x16;
typedef __attribute__((ext_vector_type(4))) float f32x4;
typedef __attribute__((ext_vector_type(4))) float f4;

#define E4M3_MAX 448.0f

__device__ inline float bf2f(ushort u) { return __uint_as_float(((unsigned)u) << 16); }
__device__ inline ushort f2bf(float f) {
  unsigned u = __float_as_uint(f);
  return (ushort)((u + 0x7FFF + ((u >> 16) & 1)) >> 16);  // RNE
}
__device__ inline unsigned pack2bf(float a, float b) {  // round-half-up
  unsigned ua = __float_as_uint(a), ub = __float_as_uint(b);
  return ((ua + 0x8000u) >> 16) | ((ub + 0x8000u) & 0xFFFF0000u);
}

// async 16B global -> LDS (direct-to-shared DMA). LDS dest must be
// wave-uniform base + lane*16 — all call sites below satisfy that.
__device__ __forceinline__ void gll16(const ushort* g, ushort* l) {
  __builtin_amdgcn_global_load_lds(
      (const __attribute__((address_space(1))) unsigned int*)g,
      (__attribute__((address_space(3))) unsigned int*)l, 16, 0, 0);
}

// e4m3 GRID value (no descale) -- exactly representable in bf16.
__device__ inline float qdq_qval(float w, float amax) {
  float scale = E4M3_MAX / fmaxf(amax, 1e-12f);
  float v = w * scale;
  float a = fmaxf(fabsf(v), 1e-30f);
  int ex;
  (void)frexpf(a, &ex);                 // floor(log2(a)) = ex-1
  float e = fminf(fmaxf((float)(ex - 1), -6.0f), 8.0f);
  float step = exp2f(e - 3.0f);
  float q = rintf(v / step) * step;     // round-half-even matches jnp.round
  return fminf(fmaxf(q, -E4M3_MAX), E4M3_MAX);
}

// all-lanes max of amaxpart[off + 0..63] (wave64 shuffle reduce, no LDS).
__device__ __forceinline__ float redpart64(const float* __restrict__ p, int tid) {
  float v = p[tid & 63];
  #pragma unroll
  for (int o = 32; o > 0; o >>= 1) v = fmaxf(v, __shfl_xor(v, o));
  return v;
}

// ---- prep1: bid<384 -> amax partial maxes (y=bid/64); else cvt3 fp32->bf16.
__global__ __launch_bounds__(256) void prep1(const float* __restrict__ W0,
                                             const float* __restrict__ W1,
                                             const float* __restrict__ W2,
                                             const float* __restrict__ b0,
                                             const float* __restrict__ b1,
                                             const float* __restrict__ b2,
                                             const float* __restrict__ Xq,
                                             const float* __restrict__ Xk,
                                             const float* __restrict__ Xv,
                                             float* __restrict__ amaxpart,
                                             ushort* __restrict__ xq,
                                             ushort* __restrict__ xk,
                                             ushort* __restrict__ xv) {
  __shared__ float wred[4];
  int bid = blockIdx.x, tid = threadIdx.x;
  if (bid < 384) {
    int y = bid >> 6, xb = bid & 63;
    const float* src = (y == 0) ? W0 : (y == 1) ? W1 : (y == 2) ? W2
                     : (y == 3) ? b0 : (y == 4) ? b1 : b2;
    int n = (y < 3) ? 1048576 : 1024;
    float m = 0.0f;
    for (int i = xb * 256 + tid; i < n; i += 64 * 256)
      m = fmaxf(m, fabsf(src[i]));
    #pragma unroll
    for (int off = 32; off > 0; off >>= 1)
      m = fmaxf(m, __shfl_xor(m, off));
    if ((tid & 63) == 0) wred[tid >> 6] = m;
    __syncthreads();
    if (tid == 0)
      amaxpart[y * 64 + xb] = fmaxf(fmaxf(wred[0], wred[1]), fmaxf(wred[2], wred[3]));
  } else {
    int t = bid - 384;
    int y = t >> 12, xb = t & 4095;
    const float* in = (y == 0) ? Xq : (y == 1) ? Xk : Xv;
    ushort* out = (y == 0) ? xq : (y == 1) ? xk : xv;
    int i = xb * 256 + tid;
    f4 v = *(const f4*)(in + (size_t)i * 4);
    uint2 o;
    o.x = (unsigned)f2bf(v[0]) | ((unsigned)f2bf(v[1]) << 16);
    o.y = (unsigned)f2bf(v[2]) | ((unsigned)f2bf(v[3]) << 16);
    *(uint2*)(out + (size_t)i * 4) = o;
  }
}

// ---- prep2: bid<768 repack W->Bt; bid<780 qvec bias; else wo_trans.
__global__ __launch_bounds__(256) void prep2(const float* __restrict__ W0,
                                             const float* __restrict__ W1,
                                             const float* __restrict__ W2,
                                             const float* __restrict__ WO,
                                             const float* __restrict__ b0,
                                             const float* __restrict__ b1,
                                             const float* __restrict__ b2,
                                             const float* __restrict__ amaxpart,
                                             float* __restrict__ amax,
                                             ushort* __restrict__ o0,
                                             ushort* __restrict__ o1,
                                             ushort* __restrict__ o2,
                                             ushort* __restrict__ woT,
                                             float* __restrict__ bq,
                                             float* __restrict__ bk,
                                             float* __restrict__ bv) {
  __shared__ float tile[64][65];
  int bid = blockIdx.x, tid = threadIdx.x;
  if (bid < 768) {
    int z = bid >> 8, r = bid & 255, hh = r >> 4, xb = r & 15;
    const float* W = (z == 0) ? W0 : (z == 1) ? W1 : W2;
    ushort* Bt = (z == 0) ? o0 : (z == 1) ? o1 : o2;
    float am = redpart64(amaxpart + z * 64, tid);
    if (r == 0 && tid == 0) amax[z] = am;   // final for gemm3_qkv (next launch)
    int d0 = xb * 64;
    int e = tid & 63, dd = tid >> 6;
    #pragma unroll
    for (int p = 0; p < 16; p++)
      tile[dd + p * 4][e] = W[(size_t)hh * 65536 + (size_t)(d0 + dd + p * 4) * 64 + e];
    __syncthreads();
    int d = tid & 63, ee = tid >> 6;
    #pragma unroll
    for (int p = 0; p < 16; p++) {
      int e2 = ee + p * 4;
      Bt[(size_t)(hh * 64 + e2) * 1024 + d0 + d] = f2bf(qdq_qval(tile[d][e2], am));
    }
  } else if (bid < 780) {
    int q = bid - 768, y = q >> 2, xb = q & 3;
    const float* b = (y == 0) ? b0 : (y == 1) ? b1 : b2;
    float* o = (y == 0) ? bq : (y == 1) ? bk : bv;
    float am = redpart64(amaxpart + (3 + y) * 64, tid);
    int idx = xb * 256 + tid;
    if (idx < 1024) {
      float qv = qdq_qval(b[idx], am);
      o[idx] = qv * (fmaxf(am, 1e-12f) * (1.0f / E4M3_MAX));
    }
  } else {
    int t = bid - 780;
    int xb = t & 15, yb = t >> 4;
    int d0 = xb * 64, he0 = yb * 64;
    int dcol = tid & 63, hr = tid >> 6;
    #pragma unroll
    for (int p = 0; p < 16; p++)
      tile[hr + p * 4][dcol] = WO[(size_t)(he0 + hr + p * 4) * 1024 + d0 + dcol];
    __syncthreads();
    int hcol = tid & 63, dr = tid >> 6;
    #pragma unroll
    for (int p = 0; p < 16; p++)
      woT[(size_t)(d0 + dr + p * 4) * 1024 + he0 + hcol] = f2bf(tile[hcol][dr + p * 4]);
  }
}

// GEMM body: C = A[M=4096][K=1024] x Bt[N][K]^T, tile 128 x TN, BK=32, 256 thr.
// m97-style: global_load_lds(16B) into UNPADDED LDS; wave-uniform dest = base+lane*16.
// QUANT=1: out bf16 *s_inv+bias; QUANT=0: out fp32 +bias.
template <int QUANT, int TN>
__device__ __forceinline__ void gemm_body(const ushort* __restrict__ A,
                                          const ushort* __restrict__ Bt,
                                          const float* __restrict__ bias, float s_inv,
                                          ushort* __restrict__ outb, float* __restrict__ outf,
                                          int bx, int by, ushort* As, ushort* Bs) {
  const int K = 1024, N = 1024;
  const int JF = TN / 32;                 // j-frags per wave
  int tid = threadIdx.x;
  int w = tid >> 6, lane = tid & 63, quad = lane >> 4, l16 = lane & 15;
  int wm = w & 1, wn = w >> 1;
  int row0 = by * 128, col0 = bx * TN;
  f32x4 acc[4][4] = {};

  for (int k0 = 0; k0 < K; k0 += 32) {
    __syncthreads();
    {
      int u = tid;                        // A tile: 128x32 = 512 units of 16B
      gll16(&A[(size_t)(row0 + (u >> 2)) * K + k0 + (u & 3) * 8], &As[u * 8]);
      u = tid + 256;
      gll16(&A[(size_t)(row0 + (u >> 2)) * K + k0 + (u & 3) * 8], &As[u * 8]);
      u = tid;                            // B tile: TN x 32 = TN*4 units
      gll16(&Bt[(size_t)(col0 + (u >> 2)) * K + k0 + (u & 3) * 8], &Bs[u * 8]);
      if (TN == 128) {
        u = tid + 256;
        gll16(&Bt[(size_t)(col0 + (u >> 2)) * K + k0 + (u & 3) * 8], &Bs[u * 8]);
      }
    }
    __syncthreads();                      // compiler drains vmcnt before barrier
    bf16x8 af[4], bfr[JF];
    #pragma unroll
    for (int i = 0; i < 4; i++)
      af[i] = *(const bf16x8*)&As[(wm * 64 + i * 16 + l16) * 32 + quad * 8];
    #pragma unroll
    for (int j = 0; j < JF; j++)
      bfr[j] = *(const bf16x8*)&Bs[(wn * (TN / 2) + j * 16 + l16) * 32 + quad * 8];
    #pragma unroll
    for (int i = 0; i < 4; i++)
      #pragma unroll
      for (int j = 0; j < JF; j++)
        acc[i][j] = __builtin_amdgcn_mfma_f32_16x16x32_bf16(af[i], bfr[j], acc[i][j], 0, 0, 0);
  }

  #pragma unroll
  for (int j = 0; j < JF; j++) {
    int col = col0 + wn * (TN / 2) + j * 16 + l16;
    float bv = bias[col];
    #pragma unroll
    for (int i = 0; i < 4; i++) {
      int row = row0 + wm * 64 + i * 16 + quad * 4;
      #pragma unroll
      for (int r = 0; r < 4; r++) {
        float v = acc[i][j][r] * s_inv + bv;
        if (QUANT) outb[(size_t)(row + r) * N + col] = f2bf(v);
        else       outf[(size_t)(row + r) * N + col] = v;
      }
    }
  }
}

// Batched QKV projection: grid (8, 32, 3) = 768 blocks.
__global__ __launch_bounds__(256) void gemm3_qkv(const ushort* __restrict__ xq,
                                                 const ushort* __restrict__ xk,
                                                 const ushort* __restrict__ xv,
                                                 const ushort* __restrict__ wq,
                                                 const ushort* __restrict__ wk,
                                                 const ushort* __restrict__ wv,
                                                 const float* __restrict__ bq,
                                                 const float* __restrict__ bk,
                                                 const float* __restrict__ bv,
                                                 const float* __restrict__ amax,
                                                 ushort* __restrict__ oq,
                                                 ushort* __restrict__ ok,
                                                 ushort* __restrict__ ov) {
  __shared__ ushort As[4096], Bs[4096];
  int z = blockIdx.z;
  const ushort* A  = (z == 0) ? xq : (z == 1) ? xk : xv;
  const ushort* Bt = (z == 0) ? wq : (z == 1) ? wk : wv;
  const float* bias = (z == 0) ? bq : (z == 1) ? bk : bv;
  ushort* out = (z == 0) ? oq : (z == 1) ? ok : ov;
  float s_inv = fmaxf(amax[z], 1e-12f) * (1.0f / E4M3_MAX);
  gemm_body<1, 128>(A, Bt, bias, s_inv, out, nullptr, blockIdx.x, blockIdx.y, As, Bs);
}

// Output projection: 128x64 tile -> grid (16, 32) = 512 blocks (2/CU).
__global__ __launch_bounds__(256) void gemm_wo(const ushort* __restrict__ A,
                                               const ushort* __restrict__ Bt,
                                               const float* __restrict__ bias,
                                               float* __restrict__ out) {
  __shared__ ushort As[4096], Bs[2048];
  gemm_body<0, 64>(A, Bt, bias, 1.0f, nullptr, out, blockIdx.x, blockIdx.y, As, Bs);
}

// ---- rot_vtrans: bid<4096 rotary on q/k; else v_trans. ----
__global__ __launch_bounds__(256) void rot_vtrans(ushort* __restrict__ qb,
                                                  ushort* __restrict__ kb,
                                                  const ushort* __restrict__ v,
                                                  ushort* __restrict__ vT) {
  __shared__ ushort tile[64][72];
  int bid = blockIdx.x, tid = threadIdx.x;
  if (bid < 4096) {
    int bs = bid;
    int s = bs & 2047;
    int e = tid & 63, w = tid >> 6;
    int j = e & 31;
    float inv_freq = exp2f((float)j * (-13.287712379549449f / 32.0f));
    float ang = (float)s * inv_freq;
    float c = cosf(ang), sn = sinf(ang);
    float sgn = (e < 32) ? -1.0f : 1.0f;
    size_t base = (size_t)bs * 1024;
    #pragma unroll
    for (int i = 0; i < 4; i++) {
      int h = w + i * 4;
      size_t idx = base + (size_t)h * 64 + e;
      float x = bf2f(qb[idx]);
      float xp = __shfl_xor(x, 32);
      qb[idx] = f2bf(x * c + sgn * xp * sn);
      float y = bf2f(kb[idx]);
      float yp = __shfl_xor(y, 32);
      kb[idx] = f2bf(y * c + sgn * yp * sn);
    }
  } else {
    int t = bid - 4096;
    int sx = t & 31, h = (t >> 5) & 15, b = t >> 9;
    int s0 = sx * 64;
    int e = tid & 63, sr = tid >> 6;
    #pragma unroll
    for (int p = 0; p < 16; p++)
      tile[sr + p * 4][e] = v[(size_t)(b * 2048 + s0 + sr + p * 4) * 1024 + h * 64 + e];
    __syncthreads();
    int sc = tid & 63, er = tid >> 6;
    #pragma unroll
    for (int p = 0; p < 16; p++)
      vT[(size_t)((b * 16 + h) * 64 + er + p * 4) * 2048 + s0 + sc] = tile[sc][er + p * 4];
  }
}

// ---- Flash v6 (r2 VERBATIM, measured 60.3us): KV-split-2 + causal q-tile
// pairing. Grid (8, 16, 2), 512 thr / 8 waves. Block bx processes q-tiles
// (15-bx) then (bx): pair cost = 17 iterations for every block.
// Per q-tile: waves 0-3 (g=0) do kv tiles [0,nt), waves 4-7 (g=1) do
// [nt,2nt), nt=qt+1, private Ks/Vs/P2 per split; LSE merge at the end.
__global__ __launch_bounds__(512, 4) void flash_mfma6(const ushort* __restrict__ qb,
                                                      const ushort* __restrict__ kb,
                                                      const ushort* __restrict__ vT,
                                                      ushort* __restrict__ zb) {
  int h = blockIdx.y, b = blockIdx.z;
  int tid = threadIdx.x;
  int w8 = tid >> 6;                     // 0..7
  int g = w8 >> 2;                       // kv split
  int w = w8 & 3;                        // q-wave within split
  int lane = tid & 63, h2 = lane >> 5, l31 = lane & 31;
  // LDS (ushorts): Ks[2][4096] | Vs[2][4096] | P2[2][9216]  = 69632 B
  __shared__ ushort sbuf[16384 + 18432];
  ushort* Ks = sbuf + g * 4096;
  ushort* Vs = sbuf + 8192 + g * 4096;
  ushort* P2 = sbuf + 16384 + g * 9216;

  const int qrow = w * 32 + l31;         // block-local q row in P2
  const float CE = 0.125f;               // 1/sqrt(64)

  // staging geometry (per split: 256 threads stage 64x64 K and V tiles)
  const int ts = tid & 255;
  const int u0 = ts, u1 = ts + 256;
  const int r0 = u0 >> 3, c0 = u0 & 7, r1 = u1 >> 3, c1 = u1 & 7;
  const int sw0 = (c0 ^ (r0 & 7)) * 8, sw1 = (c1 ^ (r1 & 7)) * 8;

  #pragma unroll 1
  for (int rep = 0; rep < 2; rep++) {
    const int qt = (rep == 0) ? (15 - (int)blockIdx.x) : (int)blockIdx.x;
    const int q0 = qt * 128;
    const int qg = q0 + w * 32 + l31;    // this lane's q (column of S^T)
    size_t qbase = ((size_t)(b * 2048 + qg)) * 1024 + (size_t)h * 64;
    bf16x8 qf[4];                        // Q B-frags: slot (h2,j) of chunk ck <- e=16ck+8h2+j
    #pragma unroll
    for (int ck = 0; ck < 4; ck++)
      qf[ck] = *(const bf16x8*)&qb[qbase + ck * 16 + h2 * 8];

    f32x16 accO[2] = {};                 // O^T: rows e (2 frags), col q
    float mrun = -INFINITY, lrun = 0.0f;

    const int nt = qt + 1;               // kv tiles per split (equal halves)
    const int kt0 = g * nt;              // first global kv tile of this split

    const ushort* ksrc0 = kb + ((size_t)(b * 2048 + kt0 * 64 + r0)) * 1024 + (size_t)h * 64 + c0 * 8;
    const ushort* ksrc1 = kb + ((size_t)(b * 2048 + kt0 * 64 + r1)) * 1024 + (size_t)h * 64 + c1 * 8;
    const ushort* vsrc0 = vT + ((size_t)((b * 16 + h) * 64 + r0)) * 2048 + kt0 * 64 + c0 * 8;
    const ushort* vsrc1 = vT + ((size_t)((b * 16 + h) * 64 + r1)) * 2048 + kt0 * 64 + c1 * 8;

    uint4 kc0 = *(const uint4*)ksrc0;    // prefetch tile 0 of this split
    uint4 kc1 = *(const uint4*)ksrc1;
    uint4 vc0 = *(const uint4*)vsrc0;
    uint4 vc1 = *(const uint4*)vsrc1;

    for (int t = 0; t < nt; t++) {
      int kt = kt0 + t;                  // global kv tile index
      __syncthreads();                   // prev iter's LDS reads done
      *(uint4*)&Ks[r0 * 64 + sw0] = kc0;
      *(uint4*)&Ks[r1 * 64 + sw1] = kc1;
      *(uint4*)&Vs[r0 * 64 + sw0] = vc0;
      *(uint4*)&Vs[r1 * 64 + sw1] = vc1;
      __syncthreads();
      if (t + 1 < nt) {                  // prefetch kt+1; in flight across compute
        kc0 = *(const uint4*)(ksrc0 + (size_t)(t + 1) * 65536);
        kc1 = *(const uint4*)(ksrc1 + (size_t)(t + 1) * 65536);
        vc0 = *(const uint4*)(vsrc0 + (t + 1) * 64);
        vc1 = *(const uint4*)(vsrc1 + (t + 1) * 64);
      }

      bool active = (kt * 64 <= q0 + w * 32 + 31);  // wave-uniform
      if (active) {
        // S^T = K . Q^T   (M=kv 2 frags of 32, K=e in 4 chunks of 16)
        f32x16 sc[2] = {};
        #pragma unroll
        for (int mf = 0; mf < 2; mf++) {
          int row = mf * 32 + l31;
          int s8 = row & 7;
          #pragma unroll
          for (int ck = 0; ck < 4; ck++) {
            bf16x8 ka = *(const bf16x8*)&Ks[row * 64 + (((2 * ck + h2) ^ s8) * 8)];
            sc[mf] = __builtin_amdgcn_mfma_f32_32x32x16_bf16(ka, qf[ck], sc[mf], 0, 0, 0);
          }
        }

        // causal mask (raw domain: -8000 * 0.125 = -1000 matches ref IGNORE)
        if (kt * 64 + 63 > q0 + w * 32) {
          #pragma unroll
          for (int mf = 0; mf < 2; mf++)
            #pragma unroll
            for (int i = 0; i < 16; i++) {
              int kv = kt * 64 + mf * 32 + (i & 3) + 8 * (i >> 2) + 4 * h2;
              sc[mf][i] = (kv > qg) ? -8000.0f : sc[mf][i];
            }
        }

        // online softmax: in-register (32 values/lane) + one xor-32 shuffle
        float tm = sc[0][0];
        #pragma unroll
        for (int i = 1; i < 16; i++) tm = fmaxf(tm, sc[0][i]);
        #pragma unroll
        for (int i = 0; i < 16; i++) tm = fmaxf(tm, sc[1][i]);
        tm = fmaxf(tm, __shfl_xor(tm, 32));
        float mnew = fmaxf(mrun, tm);
        float alpha = __expf((mrun - mnew) * CE);
        float p[2][16];
        float rs = 0.0f;
        #pragma unroll
        for (int mf = 0; mf < 2; mf++)
          #pragma unroll
          for (int i = 0; i < 16; i++) {
            float pv = __expf((sc[mf][i] - mnew) * CE);
            p[mf][i] = pv;
            rs += pv;
          }
        rs += __shfl_xor(rs, 32);
        lrun = lrun * alpha + rs;
        mrun = mnew;
        #pragma unroll
        for (int mf = 0; mf < 2; mf++)
          #pragma unroll
          for (int i = 0; i < 16; i++) accO[mf][i] *= alpha;

        // write P^T -> LDS as P2[q][kv]: lane owns row q=qrow (wave-private)
        #pragma unroll
        for (int mf = 0; mf < 2; mf++)
          #pragma unroll
          for (int m = 0; m < 4; m++) {
            uint2 w2;
            w2.x = pack2bf(p[mf][4 * m + 0], p[mf][4 * m + 1]);
            w2.y = pack2bf(p[mf][4 * m + 2], p[mf][4 * m + 3]);
            *(uint2*)&P2[qrow * 72 + 32 * mf + 8 * m + 4 * h2] = w2;
          }

        // O^T += V^T . P^T ; same-wave P2 read (compiler inserts lgkmcnt)
        #pragma unroll
        for (int ck = 0; ck < 4; ck++) {
          bf16x8 pB = *(const bf16x8*)&P2[qrow * 72 + ck * 16 + h2 * 8];
          #pragma unroll
          for (int mf = 0; mf < 2; mf++) {
            int row = mf * 32 + l31;
            bf16x8 va = *(const bf16x8*)&Vs[row * 64 + (((2 * ck + h2) ^ (row & 7)) * 8)];
            accO[mf] = __builtin_amdgcn_mfma_f32_32x32x16_bf16(va, pB, accO[mf], 0, 0, 0);
          }
        }
      }
    }

    // ---- merge the two kv-splits: log-sum-exp combine through LDS ----
    __syncthreads();                     // all compute done, LDS free
    float* mbuf = (float*)sbuf;          // 256 lanes x 35 floats (stride 35: 2-way banks)
    int midx = (w * 64 + lane) * 35;
    if (g == 1) {
      #pragma unroll
      for (int i = 0; i < 16; i++) mbuf[midx + i] = accO[0][i];
      #pragma unroll
      for (int i = 0; i < 16; i++) mbuf[midx + 16 + i] = accO[1][i];
      mbuf[midx + 32] = mrun;
      mbuf[midx + 33] = lrun;
    }
    __syncthreads();
    ushort* Osb = sbuf + 16384 + 9216;   // P2 split-1 region (past mbuf), 128 x 72
    if (g == 0) {
      float m1 = mbuf[midx + 32], l1 = mbuf[midx + 33];
      float mn = fmaxf(mrun, m1);
      float a0 = __expf((mrun - mn) * CE), a1 = __expf((m1 - mn) * CE);
      float linv = 1.0f / (lrun * a0 + l1 * a1);
      #pragma unroll
      for (int mf = 0; mf < 2; mf++)
        #pragma unroll
        for (int m = 0; m < 4; m++) {
          int e0 = 32 * mf + 8 * m + 4 * h2;
          float o0 = (accO[mf][4 * m + 0] * a0 + mbuf[midx + 16 * mf + 4 * m + 0] * a1) * linv;
          float o1 = (accO[mf][4 * m + 1] * a0 + mbuf[midx + 16 * mf + 4 * m + 1] * a1) * linv;
          float o2 = (accO[mf][4 * m + 2] * a0 + mbuf[midx + 16 * mf + 4 * m + 2] * a1) * linv;
          float o3 = (accO[mf][4 * m + 3] * a0 + mbuf[midx + 16 * mf + 4 * m + 3] * a1) * linv;
          *(unsigned*)&Osb[qrow * 72 + e0] = pack2bf(o0, o1);
          *(unsigned*)&Osb[qrow * 72 + e0 + 2] = pack2bf(o2, o3);
        }
    }
    __syncthreads();
    size_t obase = ((size_t)(b * 2048 + q0)) * 1024 + (size_t)h * 64;
    #pragma unroll
    for (int i = 0; i < 2; i++) {
      int u = tid + i * 512;             // 1024 units: 128 rows x 8 blocks
      int r = u >> 3, blk = u & 7;
      *(uint4*)&zb[obase + (size_t)r * 1024 + blk * 8] = *(const uint4*)&Osb[r * 72 + blk * 8];
    }
    // next rep's loop-top __syncthreads() orders these LDS reads vs Ks writes
  }
}

extern "C" void kernel_launch(void* const* d_in, const int* in_sizes, int n_in,
                              void* d_out, int out_size, void* d_ws, size_t ws_size,
                              hipStream_t stream) {
  const float* Xq  = (const float*)d_in[0];
  const float* Xk  = (const float*)d_in[1];
  const float* Xv  = (const float*)d_in[2];
  const float* W_Q = (const float*)d_in[3];
  const float* W_K = (const float*)d_in[4];
  const float* W_V = (const float*)d_in[5];
  const float* W_O = (const float*)d_in[6];
  const float* b_Q = (const float*)d_in[7];
  const float* b_K = (const float*)d_in[8];
  const float* b_V = (const float*)d_in[9];
  const float* b_O = (const float*)d_in[10];
  float* out = (float*)d_out;

  // ws layout (56.4 MB): amax/amaxpart/bias | weights 8.4MB | xq,xk,xv | qbf,kbf,vbf
  // vT overlays xq (dead after gemm3), zbf overlays xk (dead after gemm3/v_trans).
  char* base = (char*)d_ws;
  float*  amax = (float*)(base + 0);
  float*  amaxpart = (float*)(base + 1024);   // 6*64 floats = 1536 B
  float*  bq   = (float*)(base + 4096);
  float*  bk   = (float*)(base + 8192);
  float*  bv   = (float*)(base + 12288);
  ushort* wq   = (ushort*)(base + 16384);
  ushort* wk   = (ushort*)(base + 16384 + 2097152);
  ushort* wv   = (ushort*)(base + 16384 + 2u * 2097152);
  ushort* woT  = (ushort*)(base + 16384 + 3u * 2097152);
  ushort* xq   = (ushort*)(base + 8404992);
  ushort* xk   = (ushort*)(base + 16793600);
  ushort* xv   = (ushort*)(base + 25182208);
  ushort* qbf  = (ushort*)(base + 33570816);
  ushort* kbf  = (ushort*)(base + 41959424);
  ushort* vbf  = (ushort*)(base + 50348032);
  ushort* vT   = xq;   // xq dead after gemm3_qkv
  ushort* zbf  = xk;   // xk dead after gemm3_qkv

  // 1) amax partials (384 blocks) + fp32->bf16 convert (12288 blocks)
  prep1<<<12672, 256, 0, stream>>>(W_Q, W_K, W_V, b_Q, b_K, b_V, Xq, Xk, Xv,
                                   amaxpart, xq, xk, xv);
  // 2) weight repack (768) + bias quant (12) + W_O transpose (256)
  prep2<<<1036, 256, 0, stream>>>(W_Q, W_K, W_V, W_O, b_Q, b_K, b_V,
                                  amaxpart, amax, wq, wk, wv, woT, bq, bk, bv);
  // 3) batched QKV GEMM
  dim3 g3(8, 32, 3);
  gemm3_qkv<<<g3, 256, 0, stream>>>(xq, xk, xv, wq, wk, wv, bq, bk, bv, amax,
                                    qbf, kbf, vbf);
  // 4) rotary (4096) + V transpose (1024)
  rot_vtrans<<<5120, 256, 0, stream>>>(qbf, kbf, vbf, vT);
  // 5) flash attention (r2-verified)
  dim3 fgrid(8, 16, 2);
  flash_mfma6<<<fgrid, 512, 0, stream>>>(qbf, kbf, vT, zbf);
  // 6) output projection
  dim3 wog(16, 32);
  gemm_wo<<<wog, 256, 0, stream>>>(zbf, woT, b_O, out);
}

// Round 7
// 242.766 us; speedup vs baseline: 1.1844x; 1.0441x over previous
//
#include <hip/hip_runtime.h>
#include <math.h>

// QuantizedAttention: B=2, S=2048, D=1024, H=16, Dh=64.
// Round 12:
//  - flash_mfma9: balanced 2-blocks/CU. Confirmed twice (r5,r6): per-CU rate
//    at TWO independent 8-wave blocks = 3.8 wave-iters/us vs 2.26 at one
//    block (r7/r11 pairing) and 2.1 at one 16-wave block (r8) -> independent
//    barrier groups overlap each other's stalls. Grid (16,16,2)=512 blocks
//    (2/CU), one q-tile/block, qt = bz ? 15-bx : bx  -> co-resident blocks
//    (i, i+256) have iters (qt+1)+(16-qt) = 17 -> uniform 136 wave-iters/CU
//    in two independent groups. Body = r11 flash_mfma6 verbatim, rep loop
//    dropped. Predicted flash ~36-43us.
//  - everything else identical to round 11 (measured 253.5us total).

typedef __attribute__((ext_vector_type(8))) short bf16x8;   // 8 bf16 = 4 VGPRs
typedef __attribute__((ext_vector_type(16))) float f32x16;
typedef __attribute__((ext_vector_type(4))) float f32x4;
typedef __attribute__((ext_vector_type(4))) float f4;

#define E4M3_MAX 448.0f

__device__ inline float bf2f(ushort u) { return __uint_as_float(((unsigned)u) << 16); }
__device__ inline ushort f2bf(float f) {
  unsigned u = __float_as_uint(f);
  return (ushort)((u + 0x7FFF + ((u >> 16) & 1)) >> 16);  // RNE
}
__device__ inline unsigned pack2bf(float a, float b) {  // round-half-up
  unsigned ua = __float_as_uint(a), ub = __float_as_uint(b);
  return ((ua + 0x8000u) >> 16) | ((ub + 0x8000u) & 0xFFFF0000u);
}

// async 16B global -> LDS (direct-to-shared DMA). LDS dest must be
// wave-uniform base + lane*16 — all call sites below satisfy that.
__device__ __forceinline__ void gll16(const ushort* g, ushort* l) {
  __builtin_amdgcn_global_load_lds(
      (const __attribute__((address_space(1))) unsigned int*)g,
      (__attribute__((address_space(3))) unsigned int*)l, 16, 0, 0);
}

// e4m3 GRID value (no descale) -- exactly representable in bf16.
__device__ inline float qdq_qval(float w, float amax) {
  float scale = E4M3_MAX / fmaxf(amax, 1e-12f);
  float v = w * scale;
  float a = fmaxf(fabsf(v), 1e-30f);
  int ex;
  (void)frexpf(a, &ex);                 // floor(log2(a)) = ex-1
  float e = fminf(fmaxf((float)(ex - 1), -6.0f), 8.0f);
  float step = exp2f(e - 3.0f);
  float q = rintf(v / step) * step;     // round-half-even matches jnp.round
  return fminf(fmaxf(q, -E4M3_MAX), E4M3_MAX);
}

// all-lanes max of amaxpart[off + 0..63] (wave64 shuffle reduce, no LDS).
__device__ __forceinline__ float redpart64(const float* __restrict__ p, int tid) {
  float v = p[tid & 63];
  #pragma unroll
  for (int o = 32; o > 0; o >>= 1) v = fmaxf(v, __shfl_xor(v, o));
  return v;
}

// ---- prep1: bid<384 -> amax partial maxes (y=bid/64); else cvt3 fp32->bf16.
__global__ __launch_bounds__(256) void prep1(const float* __restrict__ W0,
                                             const float* __restrict__ W1,
                                             const float* __restrict__ W2,
                                             const float* __restrict__ b0,
                                             const float* __restrict__ b1,
                                             const float* __restrict__ b2,
                                             const float* __restrict__ Xq,
                                             const float* __restrict__ Xk,
                                             const float* __restrict__ Xv,
                                             float* __restrict__ amaxpart,
                                             ushort* __restrict__ xq,
                                             ushort* __restrict__ xk,
                                             ushort* __restrict__ xv) {
  __shared__ float wred[4];
  int bid = blockIdx.x, tid = threadIdx.x;
  if (bid < 384) {
    int y = bid >> 6, xb = bid & 63;
    const float* src = (y == 0) ? W0 : (y == 1) ? W1 : (y == 2) ? W2
                     : (y == 3) ? b0 : (y == 4) ? b1 : b2;
    int n = (y < 3) ? 1048576 : 1024;
    float m = 0.0f;
    for (int i = xb * 256 + tid; i < n; i += 64 * 256)
      m = fmaxf(m, fabsf(src[i]));
    #pragma unroll
    for (int off = 32; off > 0; off >>= 1)
      m = fmaxf(m, __shfl_xor(m, off));
    if ((tid & 63) == 0) wred[tid >> 6] = m;
    __syncthreads();
    if (tid == 0)
      amaxpart[y * 64 + xb] = fmaxf(fmaxf(wred[0], wred[1]), fmaxf(wred[2], wred[3]));
  } else {
    int t = bid - 384;
    int y = t >> 12, xb = t & 4095;
    const float* in = (y == 0) ? Xq : (y == 1) ? Xk : Xv;
    ushort* out = (y == 0) ? xq : (y == 1) ? xk : xv;
    int i = xb * 256 + tid;
    f4 v = *(const f4*)(in + (size_t)i * 4);
    uint2 o;
    o.x = (unsigned)f2bf(v[0]) | ((unsigned)f2bf(v[1]) << 16);
    o.y = (unsigned)f2bf(v[2]) | ((unsigned)f2bf(v[3]) << 16);
    *(uint2*)(out + (size_t)i * 4) = o;
  }
}

// ---- prep2: bid<768 repack W->Bt; bid<780 qvec bias; else wo_trans.
__global__ __launch_bounds__(256) void prep2(const float* __restrict__ W0,
                                             const float* __restrict__ W1,
                                             const float* __restrict__ W2,
                                             const float* __restrict__ WO,
                                             const float* __restrict__ b0,
                                             const float* __restrict__ b1,
                                             const float* __restrict__ b2,
                                             const float* __restrict__ amaxpart,
                                             float* __restrict__ amax,
                                             ushort* __restrict__ o0,
                                             ushort* __restrict__ o1,
                                             ushort* __restrict__ o2,
                                             ushort* __restrict__ woT,
                                             float* __restrict__ bq,
                                             float* __restrict__ bk,
                                             float* __restrict__ bv) {
  __shared__ float tile[64][65];
  int bid = blockIdx.x, tid = threadIdx.x;
  if (bid < 768) {
    int z = bid >> 8, r = bid & 255, hh = r >> 4, xb = r & 15;
    const float* W = (z == 0) ? W0 : (z == 1) ? W1 : W2;
    ushort* Bt = (z == 0) ? o0 : (z == 1) ? o1 : o2;
    float am = redpart64(amaxpart + z * 64, tid);
    if (r == 0 && tid == 0) amax[z] = am;   // final for gemm3_qkv (next launch)
    int d0 = xb * 64;
    int e = tid & 63, dd = tid >> 6;
    #pragma unroll
    for (int p = 0; p < 16; p++)
      tile[dd + p * 4][e] = W[(size_t)hh * 65536 + (size_t)(d0 + dd + p * 4) * 64 + e];
    __syncthreads();
    int d = tid & 63, ee = tid >> 6;
    #pragma unroll
    for (int p = 0; p < 16; p++) {
      int e2 = ee + p * 4;
      Bt[(size_t)(hh * 64 + e2) * 1024 + d0 + d] = f2bf(qdq_qval(tile[d][e2], am));
    }
  } else if (bid < 780) {
    int q = bid - 768, y = q >> 2, xb = q & 3;
    const float* b = (y == 0) ? b0 : (y == 1) ? b1 : b2;
    float* o = (y == 0) ? bq : (y == 1) ? bk : bv;
    float am = redpart64(amaxpart + (3 + y) * 64, tid);
    int idx = xb * 256 + tid;
    if (idx < 1024) {
      float qv = qdq_qval(b[idx], am);
      o[idx] = qv * (fmaxf(am, 1e-12f) * (1.0f / E4M3_MAX));
    }
  } else {
    int t = bid - 780;
    int xb = t & 15, yb = t >> 4;
    int d0 = xb * 64, he0 = yb * 64;
    int dcol = tid & 63, hr = tid >> 6;
    #pragma unroll
    for (int p = 0; p < 16; p++)
      tile[hr + p * 4][dcol] = WO[(size_t)(he0 + hr + p * 4) * 1024 + d0 + dcol];
    __syncthreads();
    int hcol = tid & 63, dr = tid >> 6;
    #pragma unroll
    for (int p = 0; p < 16; p++)
      woT[(size_t)(d0 + dr + p * 4) * 1024 + he0 + hcol] = f2bf(tile[hcol][dr + p * 4]);
  }
}

// GEMM body: C = A[M=4096][K=1024] x Bt[N][K]^T, tile 128 x TN, BK=32, 256 thr.
// m97-style: global_load_lds(16B) into UNPADDED LDS; wave-uniform dest = base+lane*16.
// QUANT=1: out bf16 *s_inv+bias; QUANT=0: out fp32 +bias.
template <int QUANT, int TN>
__device__ __forceinline__ void gemm_body(const ushort* __restrict__ A,
                                          const ushort* __restrict__ Bt,
                                          const float* __restrict__ bias, float s_inv,
                                          ushort* __restrict__ outb, float* __restrict__ outf,
                                          int bx, int by, ushort* As, ushort* Bs) {
  const int K = 1024, N = 1024;
  const int JF = TN / 32;                 // j-frags per wave
  int tid = threadIdx.x;
  int w = tid >> 6, lane = tid & 63, quad = lane >> 4, l16 = lane & 15;
  int wm = w & 1, wn = w >> 1;
  int row0 = by * 128, col0 = bx * TN;
  f32x4 acc[4][4] = {};

  for (int k0 = 0; k0 < K; k0 += 32) {
    __syncthreads();
    {
      int u = tid;                        // A tile: 128x32 = 512 units of 16B
      gll16(&A[(size_t)(row0 + (u >> 2)) * K + k0 + (u & 3) * 8], &As[u * 8]);
      u = tid + 256;
      gll16(&A[(size_t)(row0 + (u >> 2)) * K + k0 + (u & 3) * 8], &As[u * 8]);
      u = tid;                            // B tile: TN x 32 = TN*4 units
      gll16(&Bt[(size_t)(col0 + (u >> 2)) * K + k0 + (u & 3) * 8], &Bs[u * 8]);
      if (TN == 128) {
        u = tid + 256;
        gll16(&Bt[(size_t)(col0 + (u >> 2)) * K + k0 + (u & 3) * 8], &Bs[u * 8]);
      }
    }
    __syncthreads();                      // compiler drains vmcnt before barrier
    bf16x8 af[4], bfr[JF];
    #pragma unroll
    for (int i = 0; i < 4; i++)
      af[i] = *(const bf16x8*)&As[(wm * 64 + i * 16 + l16) * 32 + quad * 8];
    #pragma unroll
    for (int j = 0; j < JF; j++)
      bfr[j] = *(const bf16x8*)&Bs[(wn * (TN / 2) + j * 16 + l16) * 32 + quad * 8];
    #pragma unroll
    for (int i = 0; i < 4; i++)
      #pragma unroll
      for (int j = 0; j < JF; j++)
        acc[i][j] = __builtin_amdgcn_mfma_f32_16x16x32_bf16(af[i], bfr[j], acc[i][j], 0, 0, 0);
  }

  #pragma unroll
  for (int j = 0; j < JF; j++) {
    int col = col0 + wn * (TN / 2) + j * 16 + l16;
    float bv = bias[col];
    #pragma unroll
    for (int i = 0; i < 4; i++) {
      int row = row0 + wm * 64 + i * 16 + quad * 4;
      #pragma unroll
      for (int r = 0; r < 4; r++) {
        float v = acc[i][j][r] * s_inv + bv;
        if (QUANT) outb[(size_t)(row + r) * N + col] = f2bf(v);
        else       outf[(size_t)(row + r) * N + col] = v;
      }
    }
  }
}

// Batched QKV projection: grid (8, 32, 3) = 768 blocks.
__global__ __launch_bounds__(256) void gemm3_qkv(const ushort* __restrict__ xq,
                                                 const ushort* __restrict__ xk,
                                                 const ushort* __restrict__ xv,
                                                 const ushort* __restrict__ wq,
                                                 const ushort* __restrict__ wk,
                                                 const ushort* __restrict__ wv,
                                                 const float* __restrict__ bq,
                                                 const float* __restrict__ bk,
                                                 const float* __restrict__ bv,
                                                 const float* __restrict__ amax,
                                                 ushort* __restrict__ oq,
                                                 ushort* __restrict__ ok,
                                                 ushort* __restrict__ ov) {
  __shared__ ushort As[4096], Bs[4096];
  int z = blockIdx.z;
  const ushort* A  = (z == 0) ? xq : (z == 1) ? xk : xv;
  const ushort* Bt = (z == 0) ? wq : (z == 1) ? wk : wv;
  const float* bias = (z == 0) ? bq : (z == 1) ? bk : bv;
  ushort* out = (z == 0) ? oq : (z == 1) ? ok : ov;
  float s_inv = fmaxf(amax[z], 1e-12f) * (1.0f / E4M3_MAX);
  gemm_body<1, 128>(A, Bt, bias, s_inv, out, nullptr, blockIdx.x, blockIdx.y, As, Bs);
}

// Output projection: 128x64 tile -> grid (16, 32) = 512 blocks (2/CU).
__global__ __launch_bounds__(256) void gemm_wo(const ushort* __restrict__ A,
                                               const ushort* __restrict__ Bt,
                                               const float* __restrict__ bias,
                                               float* __restrict__ out) {
  __shared__ ushort As[4096], Bs[2048];
  gemm_body<0, 64>(A, Bt, bias, 1.0f, nullptr, out, blockIdx.x, blockIdx.y, As, Bs);
}

// ---- rot_vtrans: bid<4096 rotary on q/k; else v_trans. ----
__global__ __launch_bounds__(256) void rot_vtrans(ushort* __restrict__ qb,
                                                  ushort* __restrict__ kb,
                                                  const ushort* __restrict__ v,
                                                  ushort* __restrict__ vT) {
  __shared__ ushort tile[64][72];
  int bid = blockIdx.x, tid = threadIdx.x;
  if (bid < 4096) {
    int bs = bid;
    int s = bs & 2047;
    int e = tid & 63, w = tid >> 6;
    int j = e & 31;
    float inv_freq = exp2f((float)j * (-13.287712379549449f / 32.0f));
    float ang = (float)s * inv_freq;
    float c = cosf(ang), sn = sinf(ang);
    float sgn = (e < 32) ? -1.0f : 1.0f;
    size_t base = (size_t)bs * 1024;
    #pragma unroll
    for (int i = 0; i < 4; i++) {
      int h = w + i * 4;
      size_t idx = base + (size_t)h * 64 + e;
      float x = bf2f(qb[idx]);
      float xp = __shfl_xor(x, 32);
      qb[idx] = f2bf(x * c + sgn * xp * sn);
      float y = bf2f(kb[idx]);
      float yp = __shfl_xor(y, 32);
      kb[idx] = f2bf(y * c + sgn * yp * sn);
    }
  } else {
    int t = bid - 4096;
    int sx = t & 31, h = (t >> 5) & 15, b = t >> 9;
    int s0 = sx * 64;
    int e = tid & 63, sr = tid >> 6;
    #pragma unroll
    for (int p = 0; p < 16; p++)
      tile[sr + p * 4][e] = v[(size_t)(b * 2048 + s0 + sr + p * 4) * 1024 + h * 64 + e];
    __syncthreads();
    int sc = tid & 63, er = tid >> 6;
    #pragma unroll
    for (int p = 0; p < 16; p++)
      vT[(size_t)((b * 16 + h) * 64 + er + p * 4) * 2048 + s0 + sc] = tile[sc][er + p * 4];
  }
}

// ---- Flash v9: r11 body, balanced 2-blocks/CU. Grid (16,16,2) = 512 blocks,
// 512 thr / 8 waves, one q-tile per block, qt = bz ? 15-bx : bx (bijective:
// b=0 sweeps qt=bx, b=1 sweeps 15-bx). Co-resident blocks (i, i+256) have
// (qt+1)+(16-qt)=17 block-iters -> uniform per-CU work in TWO independent
// 8-wave barrier groups (the confirmed 3.8 wave-iters/us configuration).
// Per q-tile: waves 0-3 (g=0) do kv tiles [0,nt), waves 4-7 (g=1) do
// [nt,2nt), nt=qt+1, private Ks/Vs/P2 per split; LSE merge at the end.
__global__ __launch_bounds__(512, 4) void flash_mfma9(const ushort* __restrict__ qb,
                                                      const ushort* __restrict__ kb,
                                                      const ushort* __restrict__ vT,
                                                      ushort* __restrict__ zb) {
  int h = blockIdx.y, b = blockIdx.z;
  int tid = threadIdx.x;
  int w8 = tid >> 6;                     // 0..7
  int g = w8 >> 2;                       // kv split
  int w = w8 & 3;                        // q-wave within split
  int lane = tid & 63, h2 = lane >> 5, l31 = lane & 31;
  // LDS (ushorts): Ks[2][4096] | Vs[2][4096] | P2[2][9216]  = 69632 B
  __shared__ ushort sbuf[16384 + 18432];
  ushort* Ks = sbuf + g * 4096;
  ushort* Vs = sbuf + 8192 + g * 4096;
  ushort* P2 = sbuf + 16384 + g * 9216;

  const int qrow = w * 32 + l31;         // block-local q row in P2
  const float CE = 0.125f;               // 1/sqrt(64)

  // staging geometry (per split: 256 threads stage 64x64 K and V tiles)
  const int ts = tid & 255;
  const int u0 = ts, u1 = ts + 256;
  const int r0 = u0 >> 3, c0 = u0 & 7, r1 = u1 >> 3, c1 = u1 & 7;
  const int sw0 = (c0 ^ (r0 & 7)) * 8, sw1 = (c1 ^ (r1 & 7)) * 8;

  const int qt = (blockIdx.z == 0) ? (int)blockIdx.x : 15 - (int)blockIdx.x;
  const int q0 = qt * 128;
  const int qg = q0 + w * 32 + l31;      // this lane's q (column of S^T)
  size_t qbase = ((size_t)(b * 2048 + qg)) * 1024 + (size_t)h * 64;
  bf16x8 qf[4];                          // Q B-frags: slot (h2,j) of chunk ck <- e=16ck+8h2+j
  #pragma unroll
  for (int ck = 0; ck < 4; ck++)
    qf[ck] = *(const bf16x8*)&qb[qbase + ck * 16 + h2 * 8];

  f32x16 accO[2] = {};                   // O^T: rows e (2 frags), col q
  float mrun = -INFINITY, lrun = 0.0f;

  const int nt = qt + 1;                 // kv tiles per split (equal halves)
  const int kt0 = g * nt;                // first global kv tile of this split

  const ushort* ksrc0 = kb + ((size_t)(b * 2048 + kt0 * 64 + r0)) * 1024 + (size_t)h * 64 + c0 * 8;
  const ushort* ksrc1 = kb + ((size_t)(b * 2048 + kt0 * 64 + r1)) * 1024 + (size_t)h * 64 + c1 * 8;
  const ushort* vsrc0 = vT + ((size_t)((b * 16 + h) * 64 + r0)) * 2048 + kt0 * 64 + c0 * 8;
  const ushort* vsrc1 = vT + ((size_t)((b * 16 + h) * 64 + r1)) * 2048 + kt0 * 64 + c1 * 8;

  uint4 kc0 = *(const uint4*)ksrc0;      // prefetch tile 0 of this split
  uint4 kc1 = *(const uint4*)ksrc1;
  uint4 vc0 = *(const uint4*)vsrc0;
  uint4 vc1 = *(const uint4*)vsrc1;

  for (int t = 0; t < nt; t++) {
    int kt = kt0 + t;                    // global kv tile index
    __syncthreads();                     // prev iter's LDS reads done
    *(uint4*)&Ks[r0 * 64 + sw0] = kc0;
    *(uint4*)&Ks[r1 * 64 + sw1] = kc1;
    *(uint4*)&Vs[r0 * 64 + sw0] = vc0;
    *(uint4*)&Vs[r1 * 64 + sw1] = vc1;
    __syncthreads();
    if (t + 1 < nt) {                    // prefetch kt+1; in flight across compute
      kc0 = *(const uint4*)(ksrc0 + (size_t)(t + 1) * 65536);
      kc1 = *(const uint4*)(ksrc1 + (size_t)(t + 1) * 65536);
      vc0 = *(const uint4*)(vsrc0 + (t + 1) * 64);
      vc1 = *(const uint4*)(vsrc1 + (t + 1) * 64);
    }

    bool active = (kt * 64 <= q0 + w * 32 + 31);  // wave-uniform
    if (active) {
      // S^T = K . Q^T   (M=kv 2 frags of 32, K=e in 4 chunks of 16)
      f32x16 sc[2] = {};
      #pragma unroll
      for (int mf = 0; mf < 2; mf++) {
        int row = mf * 32 + l31;
        int s8 = row & 7;
        #pragma unroll
        for (int ck = 0; ck < 4; ck++) {
          bf16x8 ka = *(const bf16x8*)&Ks[row * 64 + (((2 * ck + h2) ^ s8) * 8)];
          sc[mf] = __builtin_amdgcn_mfma_f32_32x32x16_bf16(ka, qf[ck], sc[mf], 0, 0, 0);
        }
      }

      // causal mask (raw domain: -8000 * 0.125 = -1000 matches ref IGNORE)
      if (kt * 64 + 63 > q0 + w * 32) {
        #pragma unroll
        for (int mf = 0; mf < 2; mf++)
          #pragma unroll
          for (int i = 0; i < 16; i++) {
            int kv = kt * 64 + mf * 32 + (i & 3) + 8 * (i >> 2) + 4 * h2;
            sc[mf][i] = (kv > qg) ? -8000.0f : sc[mf][i];
          }
      }

      // online softmax: in-register (32 values/lane) + one xor-32 shuffle
      float tm = sc[0][0];
      #pragma unroll
      for (int i = 1; i < 16; i++) tm = fmaxf(tm, sc[0][i]);
      #pragma unroll
      for (int i = 0; i < 16; i++) tm = fmaxf(tm, sc[1][i]);
      tm = fmaxf(tm, __shfl_xor(tm, 32));
      float mnew = fmaxf(mrun, tm);
      float alpha = __expf((mrun - mnew) * CE);
      float p[2][16];
      float rs = 0.0f;
      #pragma unroll
      for (int mf = 0; mf < 2; mf++)
        #pragma unroll
        for (int i = 0; i < 16; i++) {
          float pv = __expf((sc[mf][i] - mnew) * CE);
          p[mf][i] = pv;
          rs += pv;
        }
      rs += __shfl_xor(rs, 32);
      lrun = lrun * alpha + rs;
      mrun = mnew;
      #pragma unroll
      for (int mf = 0; mf < 2; mf++)
        #pragma unroll
        for (int i = 0; i < 16; i++) accO[mf][i] *= alpha;

      // write P^T -> LDS as P2[q][kv]: lane owns row q=qrow (wave-private)
      #pragma unroll
      for (int mf = 0; mf < 2; mf++)
        #pragma unroll
        for (int m = 0; m < 4; m++) {
          uint2 w2;
          w2.x = pack2bf(p[mf][4 * m + 0], p[mf][4 * m + 1]);
          w2.y = pack2bf(p[mf][4 * m + 2], p[mf][4 * m + 3]);
          *(uint2*)&P2[qrow * 72 + 32 * mf + 8 * m + 4 * h2] = w2;
        }

      // O^T += V^T . P^T ; same-wave P2 read (compiler inserts lgkmcnt)
      #pragma unroll
      for (int ck = 0; ck < 4; ck++) {
        bf16x8 pB = *(const bf16x8*)&P2[qrow * 72 + ck * 16 + h2 * 8];
        #pragma unroll
        for (int mf = 0; mf < 2; mf++) {
          int row = mf * 32 + l31;
          bf16x8 va = *(const bf16x8*)&Vs[row * 64 + (((2 * ck + h2) ^ (row & 7)) * 8)];
          accO[mf] = __builtin_amdgcn_mfma_f32_32x32x16_bf16(va, pB, accO[mf], 0, 0, 0);
        }
      }
    }
  }

  // ---- merge the two kv-splits: log-sum-exp combine through LDS ----
  __syncthreads();                       // all compute done, LDS free
  float* mbuf = (float*)sbuf;            // 256 lanes x 35 floats (stride 35: 2-way banks)
  int midx = (w * 64 + lane) * 35;
  if (g == 1) {
    #pragma unroll
    for (int i = 0; i < 16; i++) mbuf[midx + i] = accO[0][i];
    #pragma unroll
    for (int i = 0; i < 16; i++) mbuf[midx + 16 + i] = accO[1][i];
    mbuf[midx + 32] = mrun;
    mbuf[midx + 33] = lrun;
  }
  __syncthreads();
  ushort* Osb = sbuf + 16384 + 9216;     // P2 split-1 region (past mbuf), 128 x 72
  if (g == 0) {
    float m1 = mbuf[midx + 32], l1 = mbuf[midx + 33];
    float mn = fmaxf(mrun, m1);
    float a0 = __expf((mrun - mn) * CE), a1 = __expf((m1 - mn) * CE);
    float linv = 1.0f / (lrun * a0 + l1 * a1);
    #pragma unroll
    for (int mf = 0; mf < 2; mf++)
      #pragma unroll
      for (int m = 0; m < 4; m++) {
        int e0 = 32 * mf + 8 * m + 4 * h2;
        float o0 = (accO[mf][4 * m + 0] * a0 + mbuf[midx + 16 * mf + 4 * m + 0] * a1) * linv;
        float o1 = (accO[mf][4 * m + 1] * a0 + mbuf[midx + 16 * mf + 4 * m + 1] * a1) * linv;
        float o2 = (accO[mf][4 * m + 2] * a0 + mbuf[midx + 16 * mf + 4 * m + 2] * a1) * linv;
        float o3 = (accO[mf][4 * m + 3] * a0 + mbuf[midx + 16 * mf + 4 * m + 3] * a1) * linv;
        *(unsigned*)&Osb[qrow * 72 + e0] = pack2bf(o0, o1);
        *(unsigned*)&Osb[qrow * 72 + e0 + 2] = pack2bf(o2, o3);
      }
  }
  __syncthreads();
  size_t obase = ((size_t)(b * 2048 + q0)) * 1024 + (size_t)h * 64;
  #pragma unroll
  for (int i = 0; i < 2; i++) {
    int u = tid + i * 512;               // 1024 units: 128 rows x 8 blocks
    int r = u >> 3, blk = u & 7;
    *(uint4*)&zb[obase + (size_t)r * 1024 + blk * 8] = *(const uint4*)&Osb[r * 72 + blk * 8];
  }
}

extern "C" void kernel_launch(void* const* d_in, const int* in_sizes, int n_in,
                              void* d_out, int out_size, void* d_ws, size_t ws_size,
                              hipStream_t stream) {
  const float* Xq  = (const float*)d_in[0];
  const float* Xk  = (const float*)d_in[1];
  const float* Xv  = (const float*)d_in[2];
  const float* W_Q = (const float*)d_in[3];
  const float* W_K = (const float*)d_in[4];
  const float* W_V = (const float*)d_in[5];
  const float* W_O = (const float*)d_in[6];
  const float* b_Q = (const float*)d_in[7];
  const float* b_K = (const float*)d_in[8];
  const float* b_V = (const float*)d_in[9];
  const float* b_O = (const float*)d_in[10];
  float* out = (float*)d_out;

  // ws layout (56.4 MB): amax/amaxpart/bias | weights 8.4MB | xq,xk,xv | qbf,kbf,vbf
  // vT overlays xq (dead after gemm3), zbf overlays xk (dead after gemm3/v_trans).
  char* base = (char*)d_ws;
  float*  amax = (float*)(base + 0);
  float*  amaxpart = (float*)(base + 1024);   // 6*64 floats = 1536 B
  float*  bq   = (float*)(base + 4096);
  float*  bk   = (float*)(base + 8192);
  float*  bv   = (float*)(base + 12288);
  ushort* wq   = (ushort*)(base + 16384);
  ushort* wk   = (ushort*)(base + 16384 + 2097152);
  ushort* wv   = (ushort*)(base + 16384 + 2u * 2097152);
  ushort* woT  = (ushort*)(base + 16384 + 3u * 2097152);
  ushort* xq   = (ushort*)(base + 8404992);
  ushort* xk   = (ushort*)(base + 16793600);
  ushort* xv   = (ushort*)(base + 25182208);
  ushort* qbf  = (ushort*)(base + 33570816);
  ushort* kbf  = (ushort*)(base + 41959424);
  ushort* vbf  = (ushort*)(base + 50348032);
  ushort* vT   = xq;   // xq dead after gemm3_qkv
  ushort* zbf  = xk;   // xk dead after gemm3_qkv

  // 1) amax partials (384 blocks) + fp32->bf16 convert (12288 blocks)
  prep1<<<12672, 256, 0, stream>>>(W_Q, W_K, W_V, b_Q, b_K, b_V, Xq, Xk, Xv,
                                   amaxpart, xq, xk, xv);
  // 2) weight repack (768) + bias quant (12) + W_O transpose (256)
  prep2<<<1036, 256, 0, stream>>>(W_Q, W_K, W_V, W_O, b_Q, b_K, b_V,
                                  amaxpart, amax, wq, wk, wv, woT, bq, bk, bv);
  // 3) batched QKV GEMM
  dim3 g3(8, 32, 3);
  gemm3_qkv<<<g3, 256, 0, stream>>>(xq, xk, xv, wq, wk, wv, bq, bk, bv, amax,
                                    qbf, kbf, vbf);
  // 4) rotary (4096) + V transpose (1024)
  rot_vtrans<<<5120, 256, 0, stream>>>(qbf, kbf, vbf, vT);
  // 5) flash attention: balanced 2-blocks/CU
  dim3 fgrid(16, 16, 2);
  flash_mfma9<<<fgrid, 512, 0, stream>>>(qbf, kbf, vT, zbf);
  // 6) output projection
  dim3 wog(16, 32);
  gemm_wo<<<wog, 256, 0, stream>>>(zbf, woT, b_O, out);
}